// Round 5
// baseline (208.357 us; speedup 1.0000x reference)
//
#include <hip/hip_runtime.h>
#include <math.h>

// Problem constants (match reference: B,C,W,H,D = 2,256,32,32,32)
#define Bc   2
#define Cc   256
#define Nn   32768            // W*H*D
#define CHc  128              // C/2
#define LN_EPS 1e-5f

// Fused-kernel tiling
#define TN    64              // spatial positions per tile (block)
#define TPB   512             // threads per block (8 waves)
#define NQ    16              // n-quads per tile (TN/4)
#define CG    32              // channel groups
#define CPG   8               // channels per group (Cc/CG)
#define GRIDX (Nn / TN)       // 512 -> x Bc = 1024 blocks

// ---------------------------------------------------------------------------
// Fused kernel: one HBM pass over S and T, TWO barriers per block total.
// Thread t: nq = t&15 (n-quad), cg = t>>4 (8 channels). Wave = 4 consecutive
// cg values x 16 nq -> the per-n mask partial collapses across the wave's
// 4 channel subgroups with 2 shfl_xor rounds (no barrier); 8 wave-partials
// land in LDS, one barrier, every thread sums them. e = exp(mask + bias),
// UNSHIFTED softmax (shift-invariant; |mask| <~ 2 for this data, fp32-exact;
// verified absmax 0.0 in R4). Epilogue: channel sums through 3 padded LDS
// buffers, one more barrier, one batch of atomics.
// ---------------------------------------------------------------------------
__global__ __launch_bounds__(TPB) void gc_fused(
    const float* __restrict__ S, const float* __restrict__ T,
    const float* __restrict__ wms, const float* __restrict__ bms,
    const float* __restrict__ wmt, const float* __restrict__ bmt,
    float* __restrict__ ctxnum,   // [2][Bc][Cc] raw weighted sums
    float* __restrict__ rowsum,   // [Bc][Cc]
    float* __restrict__ den,      // [2][Bc] softmax denominators
    float* __restrict__ sumsq) {  // [1]
  const int b    = blockIdx.y;
  const int tid  = threadIdx.x;
  const int nq   = tid & (NQ - 1);
  const int cg   = tid >> 4;
  const int wv   = tid >> 6;
  const int lane = tid & 63;
  const int c0   = cg * CPG;
  const int n0   = blockIdx.x * TN + nq * 4;

  __shared__ float4 mredw[2][8][NQ];   // 4 KB  wave-level mask partials
  __shared__ float  credA[Cc * 17];    // 17 KB ctx_s channel partials
  __shared__ float  credB[Cc * 17];    // 17 KB ctx_t channel partials
  __shared__ float  credC[Cc * 17];    // 17 KB rowsum channel partials
  __shared__ float  sqred[8];
  __shared__ float  denred[2][NQ];

  const float bS = bms[0];
  const float bT = bmt[0];

  const float* Sp = S + ((size_t)b * Cc + c0) * Nn + n0;
  const float* Tp = T + ((size_t)b * Cc + c0) * Nn + n0;

  float4 s4[CPG], t4[CPG];
#pragma unroll
  for (int i = 0; i < CPG; ++i) s4[i] = *(const float4*)(Sp + (size_t)i * Nn);
#pragma unroll
  for (int i = 0; i < CPG; ++i) t4[i] = *(const float4*)(Tp + (size_t)i * Nn);

  float wS[CPG], wT[CPG];
#pragma unroll
  for (int i = 0; i < CPG; ++i) { wS[i] = wms[c0 + i]; wT[i] = wmt[c0 + i]; }

  float4 ms = make_float4(0.f, 0.f, 0.f, 0.f);
  float4 mt = make_float4(0.f, 0.f, 0.f, 0.f);
  float rs[CPG];
  float sq = 0.f;
#pragma unroll
  for (int i = 0; i < CPG; ++i) {
    ms.x += wS[i] * s4[i].x; ms.y += wS[i] * s4[i].y;
    ms.z += wS[i] * s4[i].z; ms.w += wS[i] * s4[i].w;
    mt.x += wT[i] * t4[i].x; mt.y += wT[i] * t4[i].y;
    mt.z += wT[i] * t4[i].z; mt.w += wT[i] * t4[i].w;
    const float dx = s4[i].x - t4[i].x, dy = s4[i].y - t4[i].y;
    const float dz = s4[i].z - t4[i].z, dw = s4[i].w - t4[i].w;
    rs[i] = dx + dy + dz + dw;
    sq += dx * dx + dy * dy + dz * dz + dw * dw;
  }

  // butterfly across the wave's 4 cg-subgroups (lane bits 4,5) — no barrier
#pragma unroll
  for (int m = 16; m <= 32; m <<= 1) {
    ms.x += __shfl_xor(ms.x, m); ms.y += __shfl_xor(ms.y, m);
    ms.z += __shfl_xor(ms.z, m); ms.w += __shfl_xor(ms.w, m);
    mt.x += __shfl_xor(mt.x, m); mt.y += __shfl_xor(mt.y, m);
    mt.z += __shfl_xor(mt.z, m); mt.w += __shfl_xor(mt.w, m);
  }
  if (lane < NQ) { mredw[0][wv][nq] = ms; mredw[1][wv][nq] = mt; }

  // sumsq: full wave butterfly, lane 0 stashes the wave partial
#pragma unroll
  for (int m = 1; m < 64; m <<= 1) sq += __shfl_xor(sq, m);
  if (lane == 0) sqred[wv] = sq;

  __syncthreads();   // barrier 1

  float4 Ms = make_float4(0.f, 0.f, 0.f, 0.f);
  float4 Mt = make_float4(0.f, 0.f, 0.f, 0.f);
#pragma unroll
  for (int w = 0; w < 8; ++w) {
    const float4 a = mredw[0][w][nq];
    Ms.x += a.x; Ms.y += a.y; Ms.z += a.z; Ms.w += a.w;
    const float4 c = mredw[1][w][nq];
    Mt.x += c.x; Mt.y += c.y; Mt.z += c.z; Mt.w += c.w;
  }
  float4 es, et;
  es.x = __expf(Ms.x + bS); es.y = __expf(Ms.y + bS);
  es.z = __expf(Ms.z + bS); es.w = __expf(Ms.w + bS);
  et.x = __expf(Mt.x + bT); et.y = __expf(Mt.y + bT);
  et.z = __expf(Mt.z + bT); et.w = __expf(Mt.w + bT);

  if (tid < NQ) {  // cg==0 threads: one denominator contribution per nq
    denred[0][tid] = es.x + es.y + es.z + es.w;
    denred[1][tid] = et.x + et.y + et.z + et.w;
  }

  // per-channel weighted sums + stash channel partials (padded stride 17)
#pragma unroll
  for (int i = 0; i < CPG; ++i) {
    credA[(c0 + i) * 17 + nq] =
        s4[i].x * es.x + s4[i].y * es.y + s4[i].z * es.z + s4[i].w * es.w;
    credB[(c0 + i) * 17 + nq] =
        t4[i].x * et.x + t4[i].y * et.y + t4[i].z * et.z + t4[i].w * et.w;
    credC[(c0 + i) * 17 + nq] = rs[i];
  }
  __syncthreads();   // barrier 2

  if (tid < Cc) {
    float a = 0.f, c = 0.f, r = 0.f;
#pragma unroll
    for (int k = 0; k < NQ; ++k) {
      a += credA[tid * 17 + k];
      c += credB[tid * 17 + k];
      r += credC[tid * 17 + k];
    }
    atomicAdd(&ctxnum[((size_t)0 * Bc + b) * Cc + tid], a);
    atomicAdd(&ctxnum[((size_t)1 * Bc + b) * Cc + tid], c);
    atomicAdd(&rowsum[(size_t)b * Cc + tid], r);
  } else if (tid == Cc) {
    float v = 0.f;
#pragma unroll
    for (int w = 0; w < 8; ++w) v += sqred[w];
    atomicAdd(sumsq, v);
  } else if (tid == Cc + 1) {
    float a = 0.f, c = 0.f;
#pragma unroll
    for (int k = 0; k < NQ; ++k) { a += denred[0][k]; c += denred[1][k]; }
    atomicAdd(&den[0 * Bc + b], a);
    atomicAdd(&den[1 * Bc + b], c);
  }
}

// ---------------------------------------------------------------------------
// K4a: channel_add MLP per (tt,b). grid 4, block 1024. ctx = ctxnum/den at
// load time. float4 weight loads.
// ---------------------------------------------------------------------------
__global__ __launch_bounds__(1024) void gc_k4a_mlp(
    const float* __restrict__ ctxr, const float* __restrict__ den,
    const float* __restrict__ w1s, const float* __restrict__ b1s,
    const float* __restrict__ gs,  const float* __restrict__ bes,
    const float* __restrict__ w2s, const float* __restrict__ b2s,
    const float* __restrict__ w1t, const float* __restrict__ b1t,
    const float* __restrict__ gt,  const float* __restrict__ bet,
    const float* __restrict__ w2t, const float* __restrict__ b2t,
    float* __restrict__ addv) {
  const int tt  = blockIdx.x >> 1;
  const int b   = blockIdx.x & 1;
  const int tid = threadIdx.x;

  const float* w1 = tt ? w1t : w1s;
  const float* b1 = tt ? b1t : b1s;
  const float* g  = tt ? gt  : gs;
  const float* be = tt ? bet : bes;
  const float* w2 = tt ? w2t : w2s;
  const float* b2 = tt ? b2t : b2s;

  __shared__ float cxs[Cc];
  __shared__ float part[1024];
  __shared__ float hbuf[CHc];
  __shared__ float hr[CHc];
  __shared__ float2 red2[128];
  __shared__ float mu_s, rstd_s;

  if (tid < Cc)
    cxs[tid] = ctxr[((size_t)tt * Bc + b) * Cc + tid] / den[tt * Bc + b];
  __syncthreads();

  // stage 1: h[j] = sum_c ctx[c]*w1[j][c] + b1[j]   (128 j x 8 segments)
  {
    const int j = tid >> 3, s = tid & 7;
    const float* wr = w1 + j * Cc + s * 32;
    const float4* cx4 = (const float4*)(cxs + s * 32);
    float acc = 0.f;
#pragma unroll
    for (int k = 0; k < 8; ++k) {
      const float4 w = *(const float4*)(wr + k * 4);
      const float4 x = cx4[k];
      acc += w.x * x.x + w.y * x.y + w.z * x.z + w.w * x.w;
    }
    part[tid] = acc;
  }
  __syncthreads();
  if (tid < CHc) {
    float h = b1[tid];
#pragma unroll
    for (int q = 0; q < 8; ++q) h += part[tid * 8 + q];
    hbuf[tid] = h;
  }
  __syncthreads();

  // LN stats over 128
  if (tid < CHc) {
    const float v = hbuf[tid];
    red2[tid] = make_float2(v, v * v);
  }
  __syncthreads();
  for (int s = 64; s > 0; s >>= 1) {
    if (tid < s) {
      red2[tid].x += red2[tid + s].x;
      red2[tid].y += red2[tid + s].y;
    }
    __syncthreads();
  }
  if (tid == 0) {
    const float mu = red2[0].x / (float)CHc;
    const float var = red2[0].y / (float)CHc - mu * mu;
    mu_s = mu;
    rstd_s = rsqrtf(var + LN_EPS);
  }
  __syncthreads();
  if (tid < CHc) {
    const float v = (hbuf[tid] - mu_s) * rstd_s * g[tid] + be[tid];
    hr[tid] = v > 0.f ? v : 0.f;
  }
  __syncthreads();

  // stage 3: addv[c] = sum_j hr[j]*w2[c][j] + b2[c]   (256 c x 4 segments)
  {
    const int c = tid >> 2, q = tid & 3;
    const float* wr = w2 + c * CHc + q * 32;
    const float4* h4 = (const float4*)(hr + q * 32);
    float acc = 0.f;
#pragma unroll
    for (int k = 0; k < 8; ++k) {
      const float4 w = *(const float4*)(wr + k * 4);
      const float4 x = h4[k];
      acc += w.x * x.x + w.y * x.y + w.z * x.z + w.w * x.w;
    }
    part[tid] = acc;
  }
  __syncthreads();
  if (tid < Cc) {
    float acc = b2[tid];
#pragma unroll
    for (int q = 0; q < 4; ++q) acc += part[tid * 4 + q];
    addv[((size_t)tt * Bc + b) * Cc + tid] = acc;
  }
}

// ---------------------------------------------------------------------------
// K4b: final scalar. 1 block, 256 thr.
// out = (sumsq + sum_{b,c} [2*delta*rowsum + N*delta^2]) / B
// ---------------------------------------------------------------------------
__global__ __launch_bounds__(256) void gc_k4b_final(
    const float* __restrict__ addv, const float* __restrict__ rowsum,
    const float* __restrict__ sumsq, float* __restrict__ out) {
  const int tid = threadIdx.x;
  __shared__ float red[256];
  float part = 0.f;
  for (int job = tid; job < Bc * Cc; job += 256) {
    const int c = job & (Cc - 1);
    const int b = job >> 8;
    const float delta = addv[((size_t)0 * Bc + b) * Cc + c] -
                        addv[((size_t)1 * Bc + b) * Cc + c];
    part += 2.f * delta * rowsum[(size_t)b * Cc + c] +
            (float)Nn * delta * delta;
  }
  red[tid] = part;
  __syncthreads();
  for (int s = 128; s > 0; s >>= 1) {
    if (tid < s) red[tid] += red[tid + s];
    __syncthreads();
  }
  if (tid == 0) out[0] = (red[0] + sumsq[0]) / (float)Bc;
}

// ---------------------------------------------------------------------------
extern "C" void kernel_launch(void* const* d_in, const int* in_sizes, int n_in,
                              void* d_out, int out_size, void* d_ws,
                              size_t ws_size, hipStream_t stream) {
  const float* S   = (const float*)d_in[0];
  const float* T   = (const float*)d_in[1];
  const float* wms = (const float*)d_in[2];
  const float* bms = (const float*)d_in[3];
  const float* wmt = (const float*)d_in[4];
  const float* bmt = (const float*)d_in[5];
  const float* w1s = (const float*)d_in[6];
  const float* b1s = (const float*)d_in[7];
  const float* gs  = (const float*)d_in[8];
  const float* bes = (const float*)d_in[9];
  const float* w2s = (const float*)d_in[10];
  const float* b2s = (const float*)d_in[11];
  const float* w1t = (const float*)d_in[12];
  const float* b1t = (const float*)d_in[13];
  const float* gt  = (const float*)d_in[14];
  const float* bet = (const float*)d_in[15];
  const float* w2t = (const float*)d_in[16];
  const float* b2t = (const float*)d_in[17];
  float* out = (float*)d_out;

  // ws layout (floats) — accumulators first so one memset zeroes them all.
  float* ws     = (float*)d_ws;
  float* ctxnum = ws;                         // 2*B*C = 1024
  float* rowsum = ctxnum + 2 * Bc * Cc;       // B*C   = 512
  float* den    = rowsum + Bc * Cc;           // 4
  float* sumsq  = den + 4;                    // 1
  float* addv   = sumsq + 1;                  // 2*B*C = 1024

  hipMemsetAsync(d_ws, 0, (2 * Bc * Cc + Bc * Cc + 4 + 1) * sizeof(float),
                 stream);

  gc_fused<<<dim3(GRIDX, Bc), TPB, 0, stream>>>(S, T, wms, bms, wmt, bmt,
                                                ctxnum, rowsum, den, sumsq);
  gc_k4a_mlp<<<4, 1024, 0, stream>>>(ctxnum, den, w1s, b1s, gs, bes, w2s, b2s,
                                     w1t, b1t, gt, bet, w2t, b2t, addv);
  gc_k4b_final<<<1, 256, 0, stream>>>(addv, rowsum, sumsq, out);
}

// Round 6
// 207.879 us; speedup vs baseline: 1.0023x; 1.0023x over previous
//
#include <hip/hip_runtime.h>
#include <math.h>

// Problem constants (match reference: B,C,W,H,D = 2,256,32,32,32)
#define Bc   2
#define Cc   256
#define Nn   32768            // W*H*D
#define CHc  128              // C/2
#define LN_EPS 1e-5f

// Fused-kernel tiling
#define TN    64              // spatial positions per tile (block)
#define TPB   512             // threads per block (8 waves)
#define NQ    16              // n-quads per tile (TN/4)
#define CG    32              // channel groups
#define CPG   8               // channels per group (Cc/CG)
#define GRIDX (Nn / TN)       // 512 -> x Bc = 1024 blocks

// ---------------------------------------------------------------------------
// Fused kernel: one HBM pass over S and T.
// KEY (R6): the 16 tile quads (s4[8], t4[8]) must stay LIVE across the
// barrier (used for mask before, weighted sums after). R5's VGPR_Count=64
// proves the compiler was re-loading them from global (double traffic).
// __launch_bounds__(TPB, 2) allows ~256 VGPRs so the tile stays in registers;
// rs[] is no longer stored (recomputed from live s4/t4 in the epilogue);
// single reused cred buffer keeps LDS ~22 KB -> 2 blocks/CU at high VGPR.
// UNSHIFTED softmax (shift-invariant; |mask| <~ 2, fp32-exact; absmax 0.0
// verified in R4/R5).
// ---------------------------------------------------------------------------
__global__ __launch_bounds__(TPB, 2) void gc_fused(
    const float* __restrict__ S, const float* __restrict__ T,
    const float* __restrict__ wms, const float* __restrict__ bms,
    const float* __restrict__ wmt, const float* __restrict__ bmt,
    float* __restrict__ ctxnum,   // [2][Bc][Cc] raw weighted sums
    float* __restrict__ rowsum,   // [Bc][Cc]
    float* __restrict__ den,      // [2][Bc] softmax denominators
    float* __restrict__ sumsq) {  // [1]
  const int b    = blockIdx.y;
  const int tid  = threadIdx.x;
  const int nq   = tid & (NQ - 1);
  const int cg   = tid >> 4;
  const int wv   = tid >> 6;
  const int lane = tid & 63;
  const int c0   = cg * CPG;
  const int n0   = blockIdx.x * TN + nq * 4;

  __shared__ float4 mredw[2][8][NQ];   // 4 KB   wave-level mask partials
  __shared__ float  cred[Cc * 17];     // 17 KB  reused channel-partial buffer
  __shared__ float  sqred[8];
  __shared__ float  denred[2][NQ];

  const float bS = bms[0];
  const float bT = bmt[0];

  const float* Sp = S + ((size_t)b * Cc + c0) * Nn + n0;
  const float* Tp = T + ((size_t)b * Cc + c0) * Nn + n0;

  // ---- issue all 16 independent tile loads up front ----
  float4 s4[CPG], t4[CPG];
#pragma unroll
  for (int i = 0; i < CPG; ++i) s4[i] = *(const float4*)(Sp + (size_t)i * Nn);
#pragma unroll
  for (int i = 0; i < CPG; ++i) t4[i] = *(const float4*)(Tp + (size_t)i * Nn);

  float wS[CPG], wT[CPG];
#pragma unroll
  for (int i = 0; i < CPG; ++i) { wS[i] = wms[c0 + i]; wT[i] = wmt[c0 + i]; }

  // ---- mask partials (only ms/mt accumulators live besides the tile) ----
  float4 ms = make_float4(0.f, 0.f, 0.f, 0.f);
  float4 mt = make_float4(0.f, 0.f, 0.f, 0.f);
#pragma unroll
  for (int i = 0; i < CPG; ++i) {
    ms.x += wS[i] * s4[i].x; ms.y += wS[i] * s4[i].y;
    ms.z += wS[i] * s4[i].z; ms.w += wS[i] * s4[i].w;
    mt.x += wT[i] * t4[i].x; mt.y += wT[i] * t4[i].y;
    mt.z += wT[i] * t4[i].z; mt.w += wT[i] * t4[i].w;
  }

  // butterfly across the wave's 4 cg-subgroups (lane bits 4,5) — no barrier
#pragma unroll
  for (int m = 16; m <= 32; m <<= 1) {
    ms.x += __shfl_xor(ms.x, m); ms.y += __shfl_xor(ms.y, m);
    ms.z += __shfl_xor(ms.z, m); ms.w += __shfl_xor(ms.w, m);
    mt.x += __shfl_xor(mt.x, m); mt.y += __shfl_xor(mt.y, m);
    mt.z += __shfl_xor(mt.z, m); mt.w += __shfl_xor(mt.w, m);
  }
  if (lane < NQ) { mredw[0][wv][nq] = ms; mredw[1][wv][nq] = mt; }

  __syncthreads();   // barrier 1: mask partials visible

  float4 Ms = make_float4(0.f, 0.f, 0.f, 0.f);
  float4 Mt = make_float4(0.f, 0.f, 0.f, 0.f);
#pragma unroll
  for (int w = 0; w < 8; ++w) {
    const float4 a = mredw[0][w][nq];
    Ms.x += a.x; Ms.y += a.y; Ms.z += a.z; Ms.w += a.w;
    const float4 c = mredw[1][w][nq];
    Mt.x += c.x; Mt.y += c.y; Mt.z += c.z; Mt.w += c.w;
  }
  float4 es, et;
  es.x = __expf(Ms.x + bS); es.y = __expf(Ms.y + bS);
  es.z = __expf(Ms.z + bS); es.w = __expf(Ms.w + bS);
  et.x = __expf(Mt.x + bT); et.y = __expf(Mt.y + bT);
  et.z = __expf(Mt.z + bT); et.w = __expf(Mt.w + bT);

  if (tid < NQ) {  // cg==0 threads: one denominator contribution per nq
    denred[0][tid] = es.x + es.y + es.z + es.w;
    denred[1][tid] = et.x + et.y + et.z + et.w;
  }

  // ---- round 1: ctx_s channel partials ----
#pragma unroll
  for (int i = 0; i < CPG; ++i)
    cred[(c0 + i) * 17 + nq] =
        s4[i].x * es.x + s4[i].y * es.y + s4[i].z * es.z + s4[i].w * es.w;
  __syncthreads();   // barrier 2
  if (tid < Cc) {
    float a = 0.f;
#pragma unroll
    for (int k = 0; k < NQ; ++k) a += cred[tid * 17 + k];
    atomicAdd(&ctxnum[((size_t)0 * Bc + b) * Cc + tid], a);
  } else if (tid == Cc + 1) {
    float a = 0.f, c = 0.f;
#pragma unroll
    for (int k = 0; k < NQ; ++k) { a += denred[0][k]; c += denred[1][k]; }
    atomicAdd(&den[0 * Bc + b], a);
    atomicAdd(&den[1 * Bc + b], c);
  }
  __syncthreads();   // barrier 3 (cred write-after-read guard)

  // ---- round 2: ctx_t channel partials ----
#pragma unroll
  for (int i = 0; i < CPG; ++i)
    cred[(c0 + i) * 17 + nq] =
        t4[i].x * et.x + t4[i].y * et.y + t4[i].z * et.z + t4[i].w * et.w;
  __syncthreads();   // barrier 4
  if (tid < Cc) {
    float c = 0.f;
#pragma unroll
    for (int k = 0; k < NQ; ++k) c += cred[tid * 17 + k];
    atomicAdd(&ctxnum[((size_t)1 * Bc + b) * Cc + tid], c);
  }
  __syncthreads();   // barrier 5

  // ---- round 3: rowsum partials + sumsq (recomputed from live s4/t4) ----
  float sq = 0.f;
#pragma unroll
  for (int i = 0; i < CPG; ++i) {
    const float dx = s4[i].x - t4[i].x, dy = s4[i].y - t4[i].y;
    const float dz = s4[i].z - t4[i].z, dw = s4[i].w - t4[i].w;
    cred[(c0 + i) * 17 + nq] = dx + dy + dz + dw;
    sq += dx * dx + dy * dy + dz * dz + dw * dw;
  }
#pragma unroll
  for (int m = 1; m < 64; m <<= 1) sq += __shfl_xor(sq, m);
  if (lane == 0) sqred[wv] = sq;
  __syncthreads();   // barrier 6
  if (tid < Cc) {
    float r = 0.f;
#pragma unroll
    for (int k = 0; k < NQ; ++k) r += cred[tid * 17 + k];
    atomicAdd(&rowsum[(size_t)b * Cc + tid], r);
  } else if (tid == Cc) {
    float v = 0.f;
#pragma unroll
    for (int w = 0; w < 8; ++w) v += sqred[w];
    atomicAdd(sumsq, v);
  }
}

// ---------------------------------------------------------------------------
// K4a: channel_add MLP per (tt,b). grid 4, block 1024. ctx = ctxnum/den at
// load time. float4 weight loads.
// ---------------------------------------------------------------------------
__global__ __launch_bounds__(1024) void gc_k4a_mlp(
    const float* __restrict__ ctxr, const float* __restrict__ den,
    const float* __restrict__ w1s, const float* __restrict__ b1s,
    const float* __restrict__ gs,  const float* __restrict__ bes,
    const float* __restrict__ w2s, const float* __restrict__ b2s,
    const float* __restrict__ w1t, const float* __restrict__ b1t,
    const float* __restrict__ gt,  const float* __restrict__ bet,
    const float* __restrict__ w2t, const float* __restrict__ b2t,
    float* __restrict__ addv) {
  const int tt  = blockIdx.x >> 1;
  const int b   = blockIdx.x & 1;
  const int tid = threadIdx.x;

  const float* w1 = tt ? w1t : w1s;
  const float* b1 = tt ? b1t : b1s;
  const float* g  = tt ? gt  : gs;
  const float* be = tt ? bet : bes;
  const float* w2 = tt ? w2t : w2s;
  const float* b2 = tt ? b2t : b2s;

  __shared__ float cxs[Cc];
  __shared__ float part[1024];
  __shared__ float hbuf[CHc];
  __shared__ float hr[CHc];
  __shared__ float2 red2[128];
  __shared__ float mu_s, rstd_s;

  if (tid < Cc)
    cxs[tid] = ctxr[((size_t)tt * Bc + b) * Cc + tid] / den[tt * Bc + b];
  __syncthreads();

  // stage 1: h[j] = sum_c ctx[c]*w1[j][c] + b1[j]   (128 j x 8 segments)
  {
    const int j = tid >> 3, s = tid & 7;
    const float* wr = w1 + j * Cc + s * 32;
    const float4* cx4 = (const float4*)(cxs + s * 32);
    float acc = 0.f;
#pragma unroll
    for (int k = 0; k < 8; ++k) {
      const float4 w = *(const float4*)(wr + k * 4);
      const float4 x = cx4[k];
      acc += w.x * x.x + w.y * x.y + w.z * x.z + w.w * x.w;
    }
    part[tid] = acc;
  }
  __syncthreads();
  if (tid < CHc) {
    float h = b1[tid];
#pragma unroll
    for (int q = 0; q < 8; ++q) h += part[tid * 8 + q];
    hbuf[tid] = h;
  }
  __syncthreads();

  // LN stats over 128
  if (tid < CHc) {
    const float v = hbuf[tid];
    red2[tid] = make_float2(v, v * v);
  }
  __syncthreads();
  for (int s = 64; s > 0; s >>= 1) {
    if (tid < s) {
      red2[tid].x += red2[tid + s].x;
      red2[tid].y += red2[tid + s].y;
    }
    __syncthreads();
  }
  if (tid == 0) {
    const float mu = red2[0].x / (float)CHc;
    const float var = red2[0].y / (float)CHc - mu * mu;
    mu_s = mu;
    rstd_s = rsqrtf(var + LN_EPS);
  }
  __syncthreads();
  if (tid < CHc) {
    const float v = (hbuf[tid] - mu_s) * rstd_s * g[tid] + be[tid];
    hr[tid] = v > 0.f ? v : 0.f;
  }
  __syncthreads();

  // stage 3: addv[c] = sum_j hr[j]*w2[c][j] + b2[c]   (256 c x 4 segments)
  {
    const int c = tid >> 2, q = tid & 3;
    const float* wr = w2 + c * CHc + q * 32;
    const float4* h4 = (const float4*)(hr + q * 32);
    float acc = 0.f;
#pragma unroll
    for (int k = 0; k < 8; ++k) {
      const float4 w = *(const float4*)(wr + k * 4);
      const float4 x = h4[k];
      acc += w.x * x.x + w.y * x.y + w.z * x.z + w.w * x.w;
    }
    part[tid] = acc;
  }
  __syncthreads();
  if (tid < Cc) {
    float acc = b2[tid];
#pragma unroll
    for (int q = 0; q < 4; ++q) acc += part[tid * 4 + q];
    addv[((size_t)tt * Bc + b) * Cc + tid] = acc;
  }
}

// ---------------------------------------------------------------------------
// K4b: final scalar. 1 block, 256 thr.
// out = (sumsq + sum_{b,c} [2*delta*rowsum + N*delta^2]) / B
// ---------------------------------------------------------------------------
__global__ __launch_bounds__(256) void gc_k4b_final(
    const float* __restrict__ addv, const float* __restrict__ rowsum,
    const float* __restrict__ sumsq, float* __restrict__ out) {
  const int tid = threadIdx.x;
  __shared__ float red[256];
  float part = 0.f;
  for (int job = tid; job < Bc * Cc; job += 256) {
    const int c = job & (Cc - 1);
    const int b = job >> 8;
    const float delta = addv[((size_t)0 * Bc + b) * Cc + c] -
                        addv[((size_t)1 * Bc + b) * Cc + c];
    part += 2.f * delta * rowsum[(size_t)b * Cc + c] +
            (float)Nn * delta * delta;
  }
  red[tid] = part;
  __syncthreads();
  for (int s = 128; s > 0; s >>= 1) {
    if (tid < s) red[tid] += red[tid + s];
    __syncthreads();
  }
  if (tid == 0) out[0] = (red[0] + sumsq[0]) / (float)Bc;
}

// ---------------------------------------------------------------------------
extern "C" void kernel_launch(void* const* d_in, const int* in_sizes, int n_in,
                              void* d_out, int out_size, void* d_ws,
                              size_t ws_size, hipStream_t stream) {
  const float* S   = (const float*)d_in[0];
  const float* T   = (const float*)d_in[1];
  const float* wms = (const float*)d_in[2];
  const float* bms = (const float*)d_in[3];
  const float* wmt = (const float*)d_in[4];
  const float* bmt = (const float*)d_in[5];
  const float* w1s = (const float*)d_in[6];
  const float* b1s = (const float*)d_in[7];
  const float* gs  = (const float*)d_in[8];
  const float* bes = (const float*)d_in[9];
  const float* w2s = (const float*)d_in[10];
  const float* b2s = (const float*)d_in[11];
  const float* w1t = (const float*)d_in[12];
  const float* b1t = (const float*)d_in[13];
  const float* gt  = (const float*)d_in[14];
  const float* bet = (const float*)d_in[15];
  const float* w2t = (const float*)d_in[16];
  const float* b2t = (const float*)d_in[17];
  float* out = (float*)d_out;

  // ws layout (floats) — accumulators first so one memset zeroes them all.
  float* ws     = (float*)d_ws;
  float* ctxnum = ws;                         // 2*B*C = 1024
  float* rowsum = ctxnum + 2 * Bc * Cc;       // B*C   = 512
  float* den    = rowsum + Bc * Cc;           // 4
  float* sumsq  = den + 4;                    // 1
  float* addv   = sumsq + 1;                  // 2*B*C = 1024

  hipMemsetAsync(d_ws, 0, (2 * Bc * Cc + Bc * Cc + 4 + 1) * sizeof(float),
                 stream);

  gc_fused<<<dim3(GRIDX, Bc), TPB, 0, stream>>>(S, T, wms, bms, wmt, bmt,
                                                ctxnum, rowsum, den, sumsq);
  gc_k4a_mlp<<<4, 1024, 0, stream>>>(ctxnum, den, w1s, b1s, gs, bes, w2s, b2s,
                                     w1t, b1t, gt, bet, w2t, b2t, addv);
  gc_k4b_final<<<1, 256, 0, stream>>>(addv, rowsum, sumsq, out);
}